// Round 4
// baseline (232.716 us; speedup 1.0000x reference)
//
#include <hip/hip_runtime.h>
#include <hip/hip_bf16.h>

#define FDIM 128
#define BROWS 32     // i1 rows per bucket: bin = i1>>5, loc = i1&31 (5-bit pack)
#define NBLK 512     // partition blocks for hist/scatter

typedef __attribute__((ext_vector_type(8))) short short8v;
typedef __attribute__((ext_vector_type(4))) float f32x4;

// ---- bf16 helpers (manual, RNE) ----
static __device__ __forceinline__ unsigned short f2bf(float x) {
    unsigned u = __float_as_uint(x);
    unsigned r = 0x7fffu + ((u >> 16) & 1u);
    return (unsigned short)((u + r) >> 16);
}
static __device__ __forceinline__ float bf2f(unsigned short h) {
    return __uint_as_float((unsigned)h << 16);
}

// split fp32 -> bf16 hi + bf16 lo (hi+lo reproduces fp32 to ~2^-17 rel)
static __device__ __forceinline__ void split2(float v, short& h, short& l) {
    unsigned short hh = f2bf(v);
    h = (short)hh;
    l = (short)f2bf(v - bf2f(hh));
}

// ---- k0: Ws = W + W^T, pre-split into bf16 hi/lo (linear write; done ONCE,
// so gemm blocks stage with clean vector copies instead of strided transposed reads)
__global__ void make_ws2(const float* __restrict__ W,
                         unsigned short* __restrict__ WsH,
                         unsigned short* __restrict__ WsL) {
    int idx = blockIdx.x * 256 + threadIdx.x;
    int i = idx >> 7, j = idx & 127;
    float w = W[idx] + W[j * 128 + i];
    short h, l;
    split2(w, h, l);
    WsH[idx] = (unsigned short)h;
    WsL[idx] = (unsigned short)l;
}

// ---- k1: G = F @ (W + W^T) via MFMA bf16 with 3-term split (fp32-grade accuracy).
// Block: 512 thr = 8 waves, each wave a 16-row x 128-col stripe. ----
__global__ __launch_bounds__(512, 4) void gemm_mfma(
    const float* __restrict__ Fm,
    const unsigned short* __restrict__ WsH, const unsigned short* __restrict__ WsL,
    unsigned short* __restrict__ Gbf, int N) {
    __shared__ __align__(16) unsigned short sH[128 * 136];   // stride 272B
    __shared__ __align__(16) unsigned short sL[128 * 136];

    for (int k = threadIdx.x; k < 128 * 16; k += 512) {      // 16B granules
        int i = k >> 4, g = k & 15;
        *(uint4*)((char*)sH + i * 272 + g * 16) =
            *(const uint4*)((const char*)WsH + i * 256 + g * 16);
        *(uint4*)((char*)sL + i * 272 + g * 16) =
            *(const uint4*)((const char*)WsL + i * 256 + g * 16);
    }
    __syncthreads();

    const int wid  = threadIdx.x >> 6;
    const int lane = threadIdx.x & 63;
    const int ar   = lane & 15;    // A row within 16 / B col within 16
    const int kg   = lane >> 4;    // k-subgroup: k = kg*8 + j
    const int row0 = blockIdx.x * 128 + wid * 16;
    const int gr   = row0 + ar;
    const bool rv  = gr < N;
    const float* fp = Fm + (size_t)gr * FDIM;

    f32x4 acc[8];
#pragma unroll
    for (int t = 0; t < 8; ++t) acc[t] = (f32x4){0.f, 0.f, 0.f, 0.f};

#pragma unroll
    for (int ks = 0; ks < 4; ++ks) {
        const int k0 = ks * 32 + kg * 8;
        float4 fa = make_float4(0.f, 0.f, 0.f, 0.f);
        float4 fb = make_float4(0.f, 0.f, 0.f, 0.f);
        if (rv) {
            fa = *(const float4*)(fp + k0);
            fb = *(const float4*)(fp + k0 + 4);
        }
        short8v ah, al;
        {
            short h, l;
            split2(fa.x, h, l); ah[0] = h; al[0] = l;
            split2(fa.y, h, l); ah[1] = h; al[1] = l;
            split2(fa.z, h, l); ah[2] = h; al[2] = l;
            split2(fa.w, h, l); ah[3] = h; al[3] = l;
            split2(fb.x, h, l); ah[4] = h; al[4] = l;
            split2(fb.y, h, l); ah[5] = h; al[5] = l;
            split2(fb.z, h, l); ah[6] = h; al[6] = l;
            split2(fb.w, h, l); ah[7] = h; al[7] = l;
        }
#pragma unroll
        for (int ct = 0; ct < 8; ++ct) {
            const short8v bh = *(const short8v*)(sH + (ct * 16 + ar) * 136 + k0);
            const short8v bl = *(const short8v*)(sL + (ct * 16 + ar) * 136 + k0);
            acc[ct] = __builtin_amdgcn_mfma_f32_16x16x32_bf16(ah, bh, acc[ct], 0, 0, 0);
            acc[ct] = __builtin_amdgcn_mfma_f32_16x16x32_bf16(ah, bl, acc[ct], 0, 0, 0);
            acc[ct] = __builtin_amdgcn_mfma_f32_16x16x32_bf16(al, bh, acc[ct], 0, 0, 0);
        }
    }

#pragma unroll
    for (int r = 0; r < 4; ++r) {
        const int orow = row0 + kg * 4 + r;
        if (orow < N) {
#pragma unroll
            for (int ct = 0; ct < 8; ++ct)
                Gbf[(size_t)orow * FDIM + ct * 16 + ar] = f2bf(acc[ct][r]);
        }
    }
}

// ---- k2: LDS histogram per partition block -> M[k][b]; block 0 also zeroes out[] ----
__global__ __launch_bounds__(256) void k_hist(const int* __restrict__ idx, int E,
                                              int nb, unsigned* __restrict__ M,
                                              float* __restrict__ out, int Mout) {
    if (blockIdx.x == 0) {
        for (int i = threadIdx.x; i < Mout; i += 256) out[i] = 0.f;
    }
    extern __shared__ unsigned cnt[];
    for (int i = threadIdx.x; i < nb; i += 256) cnt[i] = 0;
    __syncthreads();
    int chunk = (E + NBLK - 1) / NBLK;
    int s = blockIdx.x * chunk;
    int e_end = min(E, s + chunk);
    for (int e = s + threadIdx.x; e < e_end; e += 256) {
        int i1 = idx[E + e];
        atomicAdd(&cnt[i1 >> 5], 1u);
    }
    __syncthreads();
    for (int i = threadIdx.x; i < nb; i += 256)
        M[(size_t)blockIdx.x * nb + i] = cnt[i];
}

// ---- k3a: wave-per-bucket exclusive scan over k of M[k][b]; emits tot[b] ----
__global__ __launch_bounds__(256) void k_mscan2(unsigned* __restrict__ M, int nb,
                                                unsigned* __restrict__ tot) {
    int b = blockIdx.x * 4 + (threadIdx.x >> 6);
    int lane = threadIdx.x & 63;
    if (b >= nb) return;
    unsigned m[8];
    unsigned s = 0;
#pragma unroll
    for (int j = 0; j < 8; ++j) {
        m[j] = M[(size_t)(8 * lane + j) * nb + b];
        s += m[j];
    }
    unsigned incl = s;
#pragma unroll
    for (int d = 1; d < 64; d <<= 1) {
        unsigned u = __shfl_up(incl, d, 64);
        if (lane >= d) incl += u;
    }
    unsigned run = incl - s;   // exclusive prefix
#pragma unroll
    for (int j = 0; j < 8; ++j) {
        M[(size_t)(8 * lane + j) * nb + b] = run;
        run += m[j];
    }
    if (lane == 63) tot[b] = incl;
}

// ---- k3b: single-block exclusive scan of tot -> bucketStart ----
__global__ __launch_bounds__(256) void k_bscan(const unsigned* __restrict__ tot, int nb,
                                               unsigned* __restrict__ bucketStart) {
    __shared__ unsigned wS[4];
    int t = threadIdx.x;
    unsigned v0, v1, v2, v3, v4, v5, v6, v7;
    int b0 = t * 8;
    v0 = (b0 + 0 < nb) ? tot[b0 + 0] : 0u;
    v1 = (b0 + 1 < nb) ? tot[b0 + 1] : 0u;
    v2 = (b0 + 2 < nb) ? tot[b0 + 2] : 0u;
    v3 = (b0 + 3 < nb) ? tot[b0 + 3] : 0u;
    v4 = (b0 + 4 < nb) ? tot[b0 + 4] : 0u;
    v5 = (b0 + 5 < nb) ? tot[b0 + 5] : 0u;
    v6 = (b0 + 6 < nb) ? tot[b0 + 6] : 0u;
    v7 = (b0 + 7 < nb) ? tot[b0 + 7] : 0u;
    unsigned l0 = 0, l1 = v0, l2 = l1 + v1, l3 = l2 + v2, l4 = l3 + v3,
             l5 = l4 + v4, l6 = l5 + v5, l7 = l6 + v6;
    unsigned s = l7 + v7;
    int lane = t & 63, wid = t >> 6;
    unsigned incl = s;
    for (int d = 1; d < 64; d <<= 1) {
        unsigned u = __shfl_up(incl, d, 64);
        if (lane >= d) incl += u;
    }
    if (lane == 63) wS[wid] = incl;
    __syncthreads();
    unsigned wOff = 0;
    for (int i = 0; i < wid; ++i) wOff += wS[i];
    unsigned base = wOff + incl - s;
    if (b0 + 0 < nb) bucketStart[b0 + 0] = base + l0;
    if (b0 + 1 < nb) bucketStart[b0 + 1] = base + l1;
    if (b0 + 2 < nb) bucketStart[b0 + 2] = base + l2;
    if (b0 + 3 < nb) bucketStart[b0 + 3] = base + l3;
    if (b0 + 4 < nb) bucketStart[b0 + 4] = base + l4;
    if (b0 + 5 < nb) bucketStart[b0 + 5] = base + l5;
    if (b0 + 6 < nb) bucketStart[b0 + 6] = base + l6;
    if (b0 + 7 < nb) bucketStart[b0 + 7] = base + l7;
    if (t == 255) bucketStart[nb] = base + s;
}

// ---- k4: scatter via LDS cursors (cursor = within-bucket prefix + bucketStart) ----
__global__ __launch_bounds__(256) void k_scatter(const int* __restrict__ idx,
                                                 const int* __restrict__ mol, int E,
                                                 int nb, const unsigned* __restrict__ M,
                                                 const unsigned* __restrict__ bucketStart,
                                                 unsigned* __restrict__ sortedE) {
    extern __shared__ unsigned cur[];
    for (int i = threadIdx.x; i < nb; i += 256)
        cur[i] = M[(size_t)blockIdx.x * nb + i] + bucketStart[i];
    __syncthreads();
    int chunk = (E + NBLK - 1) / NBLK;
    int s = blockIdx.x * chunk;
    int e_end = min(E, s + chunk);
    for (int e = s + threadIdx.x; e < e_end; e += 256) {
        int i0 = idx[e];
        int i1 = idx[E + e];
        int m  = mol[e];
        int b  = i1 >> 5;
        int loc = i1 & 31;
        unsigned pos = atomicAdd(&cur[b], 1u);
        sortedE[pos] = (unsigned)i0 | ((unsigned)m << 16) | ((unsigned)loc << 26);
    }
}

// ---- k5: edge kernel, all-pairs-window MFMA.
// Per 16-edge group: A = gathered G rows (fragment layout: lane er=l&15 is the edge,
// kg=l>>4 the k-slot). B = the ENTIRE 32-row F window as two loop-invariant register
// fragment sets (window rows 0-15 / 16-31) -> ZERO LDS reads and zero data-dependent
// bank conflicts in the loop. 8 MFMAs (2 indep chains) per group compute
// C[e][w] = G(i0_e).F(row0+w); the wanted element C[e][loc(e)] is selected by
// predicate: lane (loc&15)+16*(e>>2), reg e&3, tile loc>>4 (layout HW-verified by
// gemm_mfma + round-3 pass). A-fragments prefetched one iteration ahead (2x MLP). ----
__global__ __launch_bounds__(256, 5) void edge_kernel(
    const unsigned short* __restrict__ Gbf, const float* __restrict__ Fm,
    const unsigned* __restrict__ sortedE, const unsigned* __restrict__ bucketStart,
    float* __restrict__ out, int N, int Mout) {
    __shared__ __align__(16) unsigned short sFw[BROWS * 136];  // 8.5 KB, stride 272B
    __shared__ float smol[1024];                               // 4 KB

    const int b = blockIdx.x;
    const int row0 = b * BROWS;
    const int nrow = min(BROWS, N - row0);

    // stage F window as bf16, row stride 272B (17x16B -> B-frag reads 2-way = free)
    for (int k = threadIdx.x; k < nrow * 16; k += 256) {
        int r = k >> 4, g = k & 15;                   // g = 16B granule within row
        const float4* src = (const float4*)(Fm + (size_t)(row0 + r) * FDIM + g * 8);
        float4 v0 = src[0], v1 = src[1];
        unsigned u0 = (unsigned)f2bf(v0.x) | ((unsigned)f2bf(v0.y) << 16);
        unsigned u1 = (unsigned)f2bf(v0.z) | ((unsigned)f2bf(v0.w) << 16);
        unsigned u2 = (unsigned)f2bf(v1.x) | ((unsigned)f2bf(v1.y) << 16);
        unsigned u3 = (unsigned)f2bf(v1.z) | ((unsigned)f2bf(v1.w) << 16);
        *(uint4*)((char*)sFw + r * 272 + g * 16) = make_uint4(u0, u1, u2, u3);
    }
    for (int i = threadIdx.x; i < 1024; i += 256) smol[i] = 0.f;
    __syncthreads();

    const int lane = threadIdx.x & 63;
    const int wid  = threadIdx.x >> 6;     // 4 waves
    const int er = lane & 15;              // edge slot within 16-edge group
    const int kg = lane >> 4;              // k-subgroup (8 elems each)

    // loop-invariant B fragments: B[k][c] = F[rt*16 + c][k], c = er
    // (rows >= nrow hold garbage; loc(e) < nrow for valid edges so never selected)
    short8v Bf0[4], Bf1[4];
#pragma unroll
    for (int ks = 0; ks < 4; ++ks) {
        Bf0[ks] = *(const short8v*)((char*)sFw + er * 272 + ks * 64 + kg * 16);
        Bf1[ks] = *(const short8v*)((char*)sFw + (16 + er) * 272 + ks * 64 + kg * 16);
    }

    const int s = (int)bucketStart[b];
    const int e_end = (int)bucketStart[b + 1];

    int base = s + wid * 16;
    unsigned pk = 0u;
    if (base + er < e_end) pk = sortedE[base + er];
    const unsigned short* gp = Gbf + (size_t)(pk & 0xffff) * FDIM + kg * 8;
    short8v a0 = *(const short8v*)(gp);
    short8v a1 = *(const short8v*)(gp + 32);
    short8v a2 = *(const short8v*)(gp + 64);
    short8v a3 = *(const short8v*)(gp + 96);

    while (base < e_end) {
        const int nbase = base + 64;                  // 4 waves x 16 edges
        unsigned npk = 0u;
        if (nbase + er < e_end) npk = sortedE[nbase + er];
        const unsigned short* ngp = Gbf + (size_t)(npk & 0xffff) * FDIM + kg * 8;
        short8v na0 = *(const short8v*)(ngp);
        short8v na1 = *(const short8v*)(ngp + 32);
        short8v na2 = *(const short8v*)(ngp + 64);
        short8v na3 = *(const short8v*)(ngp + 96);

        f32x4 acc0 = (f32x4){0.f, 0.f, 0.f, 0.f};
        f32x4 acc1 = (f32x4){0.f, 0.f, 0.f, 0.f};
        acc0 = __builtin_amdgcn_mfma_f32_16x16x32_bf16(a0, Bf0[0], acc0, 0, 0, 0);
        acc1 = __builtin_amdgcn_mfma_f32_16x16x32_bf16(a0, Bf1[0], acc1, 0, 0, 0);
        acc0 = __builtin_amdgcn_mfma_f32_16x16x32_bf16(a1, Bf0[1], acc0, 0, 0, 0);
        acc1 = __builtin_amdgcn_mfma_f32_16x16x32_bf16(a1, Bf1[1], acc1, 0, 0, 0);
        acc0 = __builtin_amdgcn_mfma_f32_16x16x32_bf16(a2, Bf0[2], acc0, 0, 0, 0);
        acc1 = __builtin_amdgcn_mfma_f32_16x16x32_bf16(a2, Bf1[2], acc1, 0, 0, 0);
        acc0 = __builtin_amdgcn_mfma_f32_16x16x32_bf16(a3, Bf0[3], acc0, 0, 0, 0);
        acc1 = __builtin_amdgcn_mfma_f32_16x16x32_bf16(a3, Bf1[3], acc1, 0, 0, 0);

        // diagonal selection: edge ej = (lane>>4)*4 + r lives in reg r of the lane
        // with lane&15 == loc(ej)&15, tile = loc>>4
#pragma unroll
        for (int r = 0; r < 4; ++r) {
            const int ej = ((lane >> 4) << 2) | r;
            unsigned epk = __shfl(pk, ej, 64);
            int locr = (int)(epk >> 26);
            if ((base + ej < e_end) && ((locr & 15) == er)) {
                float v = (locr & 16) ? acc1[r] : acc0[r];
                atomicAdd(&smol[(epk >> 16) & 0x3ff], v);
            }
        }
        a0 = na0; a1 = na1; a2 = na2; a3 = na3;
        pk = npk;
        base = nbase;
    }
    __syncthreads();

    for (int i = threadIdx.x; i < Mout; i += 256) {
        float v = smol[i];
        if (v != 0.f) atomicAdd(&out[i], v);
    }
}

extern "C" void kernel_launch(void* const* d_in, const int* in_sizes, int n_in,
                              void* d_out, int out_size, void* d_ws, size_t ws_size,
                              hipStream_t stream) {
    const float* Fm = (const float*)d_in[0];
    const float* W  = (const float*)d_in[1];
    const int* idx  = (const int*)d_in[2];
    const int* mol  = (const int*)d_in[3];
    float* out = (float*)d_out;

    const int N = in_sizes[0] / FDIM;   // 50000
    const int E = in_sizes[3];          // 1600000

    const int nb = (N + BROWS - 1) / BROWS;   // 1563 buckets

    // workspace layout (~23 MB)
    char* ws = (char*)d_ws;
    size_t o = 0;
    unsigned short* WsH = (unsigned short*)(ws + o); o += 32 * 1024;
    unsigned short* WsL = (unsigned short*)(ws + o); o += 32 * 1024;
    unsigned short* Gbf = (unsigned short*)(ws + o); o += ((size_t)N * FDIM * 2 + 255) & ~(size_t)255;
    unsigned* sortedE = (unsigned*)(ws + o);         o += ((size_t)E * 4 + 255) & ~(size_t)255;
    unsigned* M = (unsigned*)(ws + o);               o += ((size_t)NBLK * nb * 4 + 255) & ~(size_t)255;
    unsigned* tot = (unsigned*)(ws + o);             o += ((size_t)nb * 4 + 255) & ~(size_t)255;
    unsigned* bucketStart = (unsigned*)(ws + o);     o += ((size_t)(nb + 1) * 4 + 255) & ~(size_t)255;

    make_ws2<<<64, 256, 0, stream>>>(W, WsH, WsL);
    gemm_mfma<<<(N + 127) / 128, 512, 0, stream>>>(Fm, WsH, WsL, Gbf, N);

    size_t smem = (size_t)nb * 4;
    k_hist<<<NBLK, 256, smem, stream>>>(idx, E, nb, M, out, out_size);
    k_mscan2<<<(nb + 3) / 4, 256, 0, stream>>>(M, nb, tot);
    k_bscan<<<1, 256, 0, stream>>>(tot, nb, bucketStart);
    k_scatter<<<NBLK, 256, smem, stream>>>(idx, mol, E, nb, M, bucketStart, sortedE);

    edge_kernel<<<nb, 256, 0, stream>>>(Gbf, Fm, sortedE, bucketStart, out, N, out_size);
}

// Round 5
// 206.822 us; speedup vs baseline: 1.1252x; 1.1252x over previous
//
#include <hip/hip_runtime.h>
#include <hip/hip_bf16.h>

#define FDIM 128
#define BROWS 32     // i1 rows per bucket: bin = i1>>5 (sort granularity)
#define NBLK 128     // partition blocks for hist/scatter (64B single-owner runs)

typedef __attribute__((ext_vector_type(8))) short short8v;
typedef __attribute__((ext_vector_type(4))) float f32x4;

// ---- bf16 helpers (manual, RNE) ----
static __device__ __forceinline__ unsigned short f2bf(float x) {
    unsigned u = __float_as_uint(x);
    unsigned r = 0x7fffu + ((u >> 16) & 1u);
    return (unsigned short)((u + r) >> 16);
}
static __device__ __forceinline__ float bf2f(unsigned short h) {
    return __uint_as_float((unsigned)h << 16);
}
static __device__ __forceinline__ float bf_lo(unsigned u) { return __uint_as_float(u << 16); }
static __device__ __forceinline__ float bf_hi(unsigned u) { return __uint_as_float(u & 0xffff0000u); }

// split fp32 -> bf16 hi + bf16 lo
static __device__ __forceinline__ void split2(float v, short& h, short& l) {
    unsigned short hh = f2bf(v);
    h = (short)hh;
    l = (short)f2bf(v - bf2f(hh));
}

// ---- k0: Ws = W + W^T, pre-split into bf16 hi/lo ----
__global__ void make_ws2(const float* __restrict__ W,
                         unsigned short* __restrict__ WsH,
                         unsigned short* __restrict__ WsL) {
    int idx = blockIdx.x * 256 + threadIdx.x;
    int i = idx >> 7, j = idx & 127;
    float w = W[idx] + W[j * 128 + i];
    short h, l;
    split2(w, h, l);
    WsH[idx] = (unsigned short)h;
    WsL[idx] = (unsigned short)l;
}

// ---- k1: G = F @ (W + W^T) via MFMA bf16 3-term split (harness-verified r3/r4) ----
__global__ __launch_bounds__(512, 4) void gemm_mfma(
    const float* __restrict__ Fm,
    const unsigned short* __restrict__ WsH, const unsigned short* __restrict__ WsL,
    unsigned short* __restrict__ Gbf, int N) {
    __shared__ __align__(16) unsigned short sH[128 * 136];   // stride 272B
    __shared__ __align__(16) unsigned short sL[128 * 136];

    for (int k = threadIdx.x; k < 128 * 16; k += 512) {      // 16B granules
        int i = k >> 4, g = k & 15;
        *(uint4*)((char*)sH + i * 272 + g * 16) =
            *(const uint4*)((const char*)WsH + i * 256 + g * 16);
        *(uint4*)((char*)sL + i * 272 + g * 16) =
            *(const uint4*)((const char*)WsL + i * 256 + g * 16);
    }
    __syncthreads();

    const int wid  = threadIdx.x >> 6;
    const int lane = threadIdx.x & 63;
    const int ar   = lane & 15;
    const int kg   = lane >> 4;
    const int row0 = blockIdx.x * 128 + wid * 16;
    const int gr   = row0 + ar;
    const bool rv  = gr < N;
    const float* fp = Fm + (size_t)gr * FDIM;

    f32x4 acc[8];
#pragma unroll
    for (int t = 0; t < 8; ++t) acc[t] = (f32x4){0.f, 0.f, 0.f, 0.f};

#pragma unroll
    for (int ks = 0; ks < 4; ++ks) {
        const int k0 = ks * 32 + kg * 8;
        float4 fa = make_float4(0.f, 0.f, 0.f, 0.f);
        float4 fb = make_float4(0.f, 0.f, 0.f, 0.f);
        if (rv) {
            fa = *(const float4*)(fp + k0);
            fb = *(const float4*)(fp + k0 + 4);
        }
        short8v ah, al;
        {
            short h, l;
            split2(fa.x, h, l); ah[0] = h; al[0] = l;
            split2(fa.y, h, l); ah[1] = h; al[1] = l;
            split2(fa.z, h, l); ah[2] = h; al[2] = l;
            split2(fa.w, h, l); ah[3] = h; al[3] = l;
            split2(fb.x, h, l); ah[4] = h; al[4] = l;
            split2(fb.y, h, l); ah[5] = h; al[5] = l;
            split2(fb.z, h, l); ah[6] = h; al[6] = l;
            split2(fb.w, h, l); ah[7] = h; al[7] = l;
        }
#pragma unroll
        for (int ct = 0; ct < 8; ++ct) {
            const short8v bh = *(const short8v*)(sH + (ct * 16 + ar) * 136 + k0);
            const short8v bl = *(const short8v*)(sL + (ct * 16 + ar) * 136 + k0);
            acc[ct] = __builtin_amdgcn_mfma_f32_16x16x32_bf16(ah, bh, acc[ct], 0, 0, 0);
            acc[ct] = __builtin_amdgcn_mfma_f32_16x16x32_bf16(ah, bl, acc[ct], 0, 0, 0);
            acc[ct] = __builtin_amdgcn_mfma_f32_16x16x32_bf16(al, bh, acc[ct], 0, 0, 0);
        }
    }

#pragma unroll
    for (int r = 0; r < 4; ++r) {
        const int orow = row0 + kg * 4 + r;
        if (orow < N) {
#pragma unroll
            for (int ct = 0; ct < 8; ++ct)
                Gbf[(size_t)orow * FDIM + ct * 16 + ar] = f2bf(acc[ct][r]);
        }
    }
}

// ---- k2: LDS histogram per partition block -> M[k][b]; block 0 zeroes out[] ----
__global__ __launch_bounds__(1024) void k_hist(const int* __restrict__ idx, int E,
                                               int nb, unsigned* __restrict__ M,
                                               float* __restrict__ out, int Mout) {
    if (blockIdx.x == 0) {
        for (int i = threadIdx.x; i < Mout; i += 1024) out[i] = 0.f;
    }
    extern __shared__ unsigned cnt[];
    for (int i = threadIdx.x; i < nb; i += 1024) cnt[i] = 0;
    __syncthreads();
    int chunk = (E + NBLK - 1) / NBLK;
    int s = blockIdx.x * chunk;
    int e_end = min(E, s + chunk);
    for (int e = s + threadIdx.x; e < e_end; e += 1024) {
        int i1 = idx[E + e];
        atomicAdd(&cnt[i1 >> 5], 1u);
    }
    __syncthreads();
    for (int i = threadIdx.x; i < nb; i += 1024)
        M[(size_t)blockIdx.x * nb + i] = cnt[i];
}

// ---- k3a: wave-per-bucket exclusive scan over k of M[k][b]; emits tot[b] ----
__global__ __launch_bounds__(256) void k_mscan2(unsigned* __restrict__ M, int nb,
                                                unsigned* __restrict__ tot) {
    int b = blockIdx.x * 4 + (threadIdx.x >> 6);
    int lane = threadIdx.x & 63;
    if (b >= nb) return;
    unsigned m0 = M[(size_t)(2 * lane + 0) * nb + b];
    unsigned m1 = M[(size_t)(2 * lane + 1) * nb + b];
    unsigned s = m0 + m1;
    unsigned incl = s;
#pragma unroll
    for (int d = 1; d < 64; d <<= 1) {
        unsigned u = __shfl_up(incl, d, 64);
        if (lane >= d) incl += u;
    }
    unsigned run = incl - s;   // exclusive prefix
    M[(size_t)(2 * lane + 0) * nb + b] = run; run += m0;
    M[(size_t)(2 * lane + 1) * nb + b] = run;
    if (lane == 63) tot[b] = incl;
}

// ---- k3b: single-block exclusive scan of tot -> bucketStart ----
__global__ __launch_bounds__(256) void k_bscan(const unsigned* __restrict__ tot, int nb,
                                               unsigned* __restrict__ bucketStart) {
    __shared__ unsigned wS[4];
    int t = threadIdx.x;
    unsigned v0, v1, v2, v3, v4, v5, v6, v7;
    int b0 = t * 8;
    v0 = (b0 + 0 < nb) ? tot[b0 + 0] : 0u;
    v1 = (b0 + 1 < nb) ? tot[b0 + 1] : 0u;
    v2 = (b0 + 2 < nb) ? tot[b0 + 2] : 0u;
    v3 = (b0 + 3 < nb) ? tot[b0 + 3] : 0u;
    v4 = (b0 + 4 < nb) ? tot[b0 + 4] : 0u;
    v5 = (b0 + 5 < nb) ? tot[b0 + 5] : 0u;
    v6 = (b0 + 6 < nb) ? tot[b0 + 6] : 0u;
    v7 = (b0 + 7 < nb) ? tot[b0 + 7] : 0u;
    unsigned l0 = 0, l1 = v0, l2 = l1 + v1, l3 = l2 + v2, l4 = l3 + v3,
             l5 = l4 + v4, l6 = l5 + v5, l7 = l6 + v6;
    unsigned s = l7 + v7;
    int lane = t & 63, wid = t >> 6;
    unsigned incl = s;
    for (int d = 1; d < 64; d <<= 1) {
        unsigned u = __shfl_up(incl, d, 64);
        if (lane >= d) incl += u;
    }
    if (lane == 63) wS[wid] = incl;
    __syncthreads();
    unsigned wOff = 0;
    for (int i = 0; i < wid; ++i) wOff += wS[i];
    unsigned base = wOff + incl - s;
    if (b0 + 0 < nb) bucketStart[b0 + 0] = base + l0;
    if (b0 + 1 < nb) bucketStart[b0 + 1] = base + l1;
    if (b0 + 2 < nb) bucketStart[b0 + 2] = base + l2;
    if (b0 + 3 < nb) bucketStart[b0 + 3] = base + l3;
    if (b0 + 4 < nb) bucketStart[b0 + 4] = base + l4;
    if (b0 + 5 < nb) bucketStart[b0 + 5] = base + l5;
    if (b0 + 6 < nb) bucketStart[b0 + 6] = base + l6;
    if (b0 + 7 < nb) bucketStart[b0 + 7] = base + l7;
    if (t == 255) bucketStart[nb] = base + s;
}

// ---- k4: scatter via LDS cursors. NBLK=128 + 1024thr: each (block,bucket) run
// ~8 edges x 8B = 64B -> each dest cache line written by ONE block (no XCD bounce) ----
__global__ __launch_bounds__(1024) void k_scatter(const int* __restrict__ idx,
                                                  const int* __restrict__ mol, int E,
                                                  int nb, const unsigned* __restrict__ M,
                                                  const unsigned* __restrict__ bucketStart,
                                                  uint2* __restrict__ sortedE) {
    extern __shared__ unsigned cur[];
    for (int i = threadIdx.x; i < nb; i += 1024)
        cur[i] = M[(size_t)blockIdx.x * nb + i] + bucketStart[i];
    __syncthreads();
    int chunk = (E + NBLK - 1) / NBLK;
    int s = blockIdx.x * chunk;
    int e_end = min(E, s + chunk);
    for (int e = s + threadIdx.x; e < e_end; e += 1024) {
        int i0 = idx[e];
        int i1 = idx[E + e];
        int m  = mol[e];
        int b  = i1 >> 5;
        unsigned pos = atomicAdd(&cur[b], 1u);
        sortedE[pos] = make_uint2((unsigned)i0 | ((unsigned)m << 16), (unsigned)i1);
    }
}

// ---- k5: edge kernel — flat balanced partition over sortedE (round-2 scalar-dot
// structure). G gathered bf16; F read fp32 straight from Fm (rows L1-resident since
// edges are i1-sorted -> no unpack VALU on the F side). 8 edges/wave/iter via two
// 4-edge chains + next-iter prefetch. smol flushed skip-zero into out. ----
__global__ __launch_bounds__(512, 8) void edge_kernel(
    const unsigned short* __restrict__ Gbf, const float* __restrict__ Fm,
    const uint2* __restrict__ sortedE, int E,
    float* __restrict__ out, int Mout) {
    __shared__ float smol[1024];                     // 4 KB only

    for (int i = threadIdx.x; i < 1024; i += 512) smol[i] = 0.f;
    __syncthreads();

    const int nchunk = (E + (int)gridDim.x - 1) / (int)gridDim.x;
    const int s = blockIdx.x * nchunk;
    const int e_end = min(E, s + nchunk);

    const int lane = threadIdx.x & 63;
    const int sub  = lane >> 4;      // 0..3: edge within quad
    const int t16  = lane & 15;      // feature slice
    const int off16 = t16 * 8;
    const int wid  = threadIdx.x >> 6;

    int base = s + wid * 8;
    uint2 pkA = make_uint2(0u, 0u), pkB = make_uint2(0u, 0u);
    if (base + sub < e_end)     pkA = sortedE[base + sub];
    if (base + 4 + sub < e_end) pkB = sortedE[base + 4 + sub];

    while (base < e_end) {
        const int nbase = base + 64;   // 8 waves x 8 edges
        uint2 npkA = make_uint2(0u, 0u), npkB = make_uint2(0u, 0u);
        if (nbase + sub < e_end)     npkA = sortedE[nbase + sub];
        if (nbase + 4 + sub < e_end) npkB = sortedE[nbase + 4 + sub];

        const bool vA = (base + sub) < e_end;
        const bool vB = (base + 4 + sub) < e_end;
        const uint4 gA = *(const uint4*)(Gbf + (size_t)(pkA.x & 0xffff) * FDIM + off16);
        const uint4 gB = *(const uint4*)(Gbf + (size_t)(pkB.x & 0xffff) * FDIM + off16);
        const float* fpA = Fm + (size_t)pkA.y * FDIM + off16;
        const float* fpB = Fm + (size_t)pkB.y * FDIM + off16;
        const float4 fA0 = *(const float4*)(fpA);
        const float4 fA1 = *(const float4*)(fpA + 4);
        const float4 fB0 = *(const float4*)(fpB);
        const float4 fB1 = *(const float4*)(fpB + 4);

        float pA, pB;
        pA = bf_lo(gA.x) * fA0.x;
        pA = fmaf(bf_hi(gA.x), fA0.y, pA);
        pA = fmaf(bf_lo(gA.y), fA0.z, pA);
        pA = fmaf(bf_hi(gA.y), fA0.w, pA);
        pA = fmaf(bf_lo(gA.z), fA1.x, pA);
        pA = fmaf(bf_hi(gA.z), fA1.y, pA);
        pA = fmaf(bf_lo(gA.w), fA1.z, pA);
        pA = fmaf(bf_hi(gA.w), fA1.w, pA);
        pB = bf_lo(gB.x) * fB0.x;
        pB = fmaf(bf_hi(gB.x), fB0.y, pB);
        pB = fmaf(bf_lo(gB.y), fB0.z, pB);
        pB = fmaf(bf_hi(gB.y), fB0.w, pB);
        pB = fmaf(bf_lo(gB.z), fB1.x, pB);
        pB = fmaf(bf_hi(gB.z), fB1.y, pB);
        pB = fmaf(bf_lo(gB.w), fB1.z, pB);
        pB = fmaf(bf_hi(gB.w), fB1.w, pB);

        pA += __shfl_xor(pA, 1, 16);
        pB += __shfl_xor(pB, 1, 16);
        pA += __shfl_xor(pA, 2, 16);
        pB += __shfl_xor(pB, 2, 16);
        pA += __shfl_xor(pA, 4, 16);
        pB += __shfl_xor(pB, 4, 16);
        pA += __shfl_xor(pA, 8, 16);
        pB += __shfl_xor(pB, 8, 16);

        if (t16 == 0) {
            if (vA) atomicAdd(&smol[pkA.x >> 16], pA);
            if (vB) atomicAdd(&smol[pkB.x >> 16], pB);
        }
        pkA = npkA; pkB = npkB; base = nbase;
    }
    __syncthreads();

    for (int i = threadIdx.x; i < Mout; i += 512) {
        float v = smol[i];
        if (v != 0.f) atomicAdd(&out[i], v);
    }
}

extern "C" void kernel_launch(void* const* d_in, const int* in_sizes, int n_in,
                              void* d_out, int out_size, void* d_ws, size_t ws_size,
                              hipStream_t stream) {
    const float* Fm = (const float*)d_in[0];
    const float* W  = (const float*)d_in[1];
    const int* idx  = (const int*)d_in[2];
    const int* mol  = (const int*)d_in[3];
    float* out = (float*)d_out;

    const int N = in_sizes[0] / FDIM;   // 50000
    const int E = in_sizes[3];          // 1600000

    const int nb = (N + BROWS - 1) / BROWS;   // 1563 buckets

    // workspace layout (~27 MB)
    char* ws = (char*)d_ws;
    size_t o = 0;
    unsigned short* WsH = (unsigned short*)(ws + o); o += 32 * 1024;
    unsigned short* WsL = (unsigned short*)(ws + o); o += 32 * 1024;
    unsigned short* Gbf = (unsigned short*)(ws + o); o += ((size_t)N * FDIM * 2 + 255) & ~(size_t)255;
    uint2* sortedE = (uint2*)(ws + o);               o += ((size_t)E * 8 + 255) & ~(size_t)255;
    unsigned* M = (unsigned*)(ws + o);               o += ((size_t)NBLK * nb * 4 + 255) & ~(size_t)255;
    unsigned* tot = (unsigned*)(ws + o);             o += ((size_t)nb * 4 + 255) & ~(size_t)255;
    unsigned* bucketStart = (unsigned*)(ws + o);     o += ((size_t)(nb + 1) * 4 + 255) & ~(size_t)255;

    make_ws2<<<64, 256, 0, stream>>>(W, WsH, WsL);
    gemm_mfma<<<(N + 127) / 128, 512, 0, stream>>>(Fm, WsH, WsL, Gbf, N);

    size_t smem = (size_t)nb * 4;
    k_hist<<<NBLK, 1024, smem, stream>>>(idx, E, nb, M, out, out_size);
    k_mscan2<<<(nb + 3) / 4, 256, 0, stream>>>(M, nb, tot);
    k_bscan<<<1, 256, 0, stream>>>(tot, nb, bucketStart);
    k_scatter<<<NBLK, 1024, smem, stream>>>(idx, mol, E, nb, M, bucketStart, sortedE);

    edge_kernel<<<2048, 512, 0, stream>>>(Gbf, Fm, sortedE, E, out, out_size);
}